// Round 2
// baseline (296.049 us; speedup 1.0000x reference)
//
#include <hip/hip_runtime.h>
#include <stdint.h>

#define S_ 2048
#define H_ 16

typedef short s16x8 __attribute__((ext_vector_type(8)));
typedef float f32x4 __attribute__((ext_vector_type(4)));
typedef float f32x16 __attribute__((ext_vector_type(16)));

__device__ __forceinline__ ushort f2bf(float f) {
    union { float f; uint32_t u; } v; v.f = f;
    uint32_t r = v.u + 0x7fffu + ((v.u >> 16) & 1u);
    return (ushort)(r >> 16);
}
__device__ __forceinline__ uint32_t pk2(float a, float b) {
    return (uint32_t)f2bf(a) | ((uint32_t)f2bf(b) << 16);
}

// async global->LDS, 16B per lane. LDS dest is wave-uniform base + lane*16.
__device__ __forceinline__ void gld16(ushort* lds, const ushort* g) {
    auto* gp = reinterpret_cast<uint32_t __attribute__((address_space(1)))*>(
        reinterpret_cast<uintptr_t>(g));
    auto* lp = reinterpret_cast<uint32_t __attribute__((address_space(3)))*>(
        reinterpret_cast<uintptr_t>(lds));
    __builtin_amdgcn_global_load_lds(gp, lp, 16, 0, 0);
}

// ---- X fp32 -> bf16 (one-time pass; same RNE rounding as before) ----
__global__ void cast_bf16(const float* __restrict__ src, ushort* __restrict__ dst) {
    size_t i = ((size_t)blockIdx.x * 256 + threadIdx.x) * 8;
    float4 x = *(const float4*)(src + i);
    float4 y = *(const float4*)(src + i + 4);
    s16x8 r;
    r[0] = (short)f2bf(x.x); r[1] = (short)f2bf(x.y);
    r[2] = (short)f2bf(x.z); r[3] = (short)f2bf(x.w);
    r[4] = (short)f2bf(y.x); r[5] = (short)f2bf(y.y);
    r[6] = (short)f2bf(y.z); r[7] = (short)f2bf(y.w);
    *(s16x8*)(dst + i) = r;
}

// ---- weight prep: dst[n*1024+k] = bf16(src[k*1024+n]), 4 weights in one launch ----
__global__ void transpose_k4(const float* __restrict__ s0, const float* __restrict__ s1,
                             const float* __restrict__ s2, const float* __restrict__ s3,
                             ushort* __restrict__ d0, ushort* __restrict__ d1,
                             ushort* __restrict__ d2, ushort* __restrict__ d3) {
    const int z = blockIdx.z;
    const float* src = (z == 0) ? s0 : (z == 1) ? s1 : (z == 2) ? s2 : s3;
    ushort* dst      = (z == 0) ? d0 : (z == 1) ? d1 : (z == 2) ? d2 : d3;
    __shared__ ushort t[32][33];
    int bx = blockIdx.x * 32, by = blockIdx.y * 32;
    int x = threadIdx.x;
    for (int y = threadIdx.y; y < 32; y += 8)
        t[y][x] = f2bf(src[(size_t)(by + y) * 1024 + bx + x]);
    __syncthreads();
    for (int y = threadIdx.y; y < 32; y += 8)
        dst[(size_t)(bx + y) * 1024 + by + x] = t[x][y];
}

// ---------------- GEMM: C[m,n] = A[M,K] @ Bt[N,K]^T + bias(fp32) ------------
// A: bf16 always (X is pre-cast). Staging via global_load_lds (m97 structure).
// mode 0: FP32 out[m*1024+n]
// mode 1: Q:  bf16 out[((b*16+h)*2048+s)*64+d] = v * 0.125
// mode 2: K:  bf16 out[((b*16+h)*2048+s)*64+d] = v
// mode 3: Vt: bf16 out[((b*16+h)*64+d)*2048+s] = v
__global__ void gemm_bt(const ushort* __restrict__ A,
                        const ushort* __restrict__ Bt0, const ushort* __restrict__ Bt1,
                        const ushort* __restrict__ Bt2,
                        const float* __restrict__ bi0, const float* __restrict__ bi1,
                        const float* __restrict__ bi2,
                        void* __restrict__ o0, void* __restrict__ o1,
                        void* __restrict__ o2,
                        int mode0) {
    const int z = blockIdx.z;
    const ushort* Bt  = (z == 0) ? Bt0 : (z == 1) ? Bt1 : Bt2;
    const float* bia  = (z == 0) ? bi0 : (z == 1) ? bi1 : bi2;
    void* out         = (z == 0) ? o0  : (z == 1) ? o1  : o2;
    const int mode = mode0 + z;

    __shared__ __align__(16) ushort Asm[128 * 32];
    __shared__ __align__(16) ushort Bsm[128 * 32];

    const int t = threadIdx.x;
    const int lane = t & 63, w = t >> 6;
    const int wm = w >> 1, wn = w & 1;
    const int quad = lane >> 4, l16 = lane & 15;
    const int m0 = blockIdx.y * 128, n0 = blockIdx.x * 128;
    const int K = 1024;

    const f32x4 FZ = {0.f, 0.f, 0.f, 0.f};
    f32x4 acc[4][4];
#pragma unroll
    for (int i = 0; i < 4; i++)
#pragma unroll
        for (int j = 0; j < 4; j++) acc[i][j] = FZ;

    const ushort* Ap = A  + (size_t)(m0 + (t >> 2)) * K + (t & 3) * 8;
    const ushort* Bp = Bt + (size_t)(n0 + (t >> 2)) * K + (t & 3) * 8;
    ushort* AsmW = Asm + w * 512;
    ushort* BsmW = Bsm + w * 512;

    for (int kt = 0; kt < K / 32; ++kt) {
        __syncthreads();
        gld16(AsmW,        Ap + kt * 32);
        gld16(AsmW + 2048, Ap + (size_t)64 * K + kt * 32);
        gld16(BsmW,        Bp + kt * 32);
        gld16(BsmW + 2048, Bp + (size_t)64 * K + kt * 32);
        __syncthreads();

        s16x8 a[4], b[4];
#pragma unroll
        for (int i = 0; i < 4; i++) {
            int row = wm * 64 + i * 16 + l16;
            a[i] = *(const s16x8*)((const char*)Asm + row * 64 + quad * 16);
        }
#pragma unroll
        for (int j = 0; j < 4; j++) {
            int row = wn * 64 + j * 16 + l16;
            b[j] = *(const s16x8*)((const char*)Bsm + row * 64 + quad * 16);
        }
#pragma unroll
        for (int i = 0; i < 4; i++)
#pragma unroll
            for (int j = 0; j < 4; j++)
                acc[i][j] = __builtin_amdgcn_mfma_f32_16x16x32_bf16(a[i], b[j], acc[i][j], 0, 0, 0);
    }

#pragma unroll
    for (int j = 0; j < 4; j++) {
        int n = n0 + wn * 64 + j * 16 + l16;
        float bv = bia[n];
#pragma unroll
        for (int i = 0; i < 4; i++) {
#pragma unroll
            for (int r = 0; r < 4; r++) {
                int m = m0 + wm * 64 + i * 16 + quad * 4 + r;
                float v = acc[i][j][r] + bv;
                if (mode == 0) {
                    ((float*)out)[(size_t)m * 1024 + n] = v;
                } else {
                    int b_ = m >> 11, s = m & 2047;
                    int h = n >> 6, d = n & 63;
                    if (mode == 1)
                        ((ushort*)out)[((size_t)(b_ * 16 + h) * 2048 + s) * 64 + d] = f2bf(v * 0.125f);
                    else if (mode == 2)
                        ((ushort*)out)[((size_t)(b_ * 16 + h) * 2048 + s) * 64 + d] = f2bf(v);
                    else
                        ((ushort*)out)[((size_t)(b_ * 16 + h) * 64 + d) * 2048 + s] = f2bf(v);
                }
            }
        }
    }
}

// ---------------- MFMA flash attention, swapped-operand 32x32, zero-LDS loop ----
// grid: (S/128, B*H), 256 threads = 4 independent waves, each owns 32 q-rows.
// QK^T computed as St = mfma(K, Q)  -> St[kidx][q]: lane holds col q = lane&31,
//   rows kidx = (reg&3)+8*(reg>>2)+4*(lane>>5)  (guide-verified 32x32 C/D map).
// PV computed as O^T = mfma(Vt, P^T) -> O^T[d][q]: same q-per-lane as softmax
//   state, so rescale/divide are lane-local. P^T B-frag == P A-frag layout
//   (col=lane&31=q, k=8*hi+e), assembled in-register via __shfl_xor(.,32).
// K/V fragments are contiguous 16B global loads (L2-resident per bh: 512KB).
__global__ __launch_bounds__(256, 4) void attn(const ushort* __restrict__ q_ws,
                                               const ushort* __restrict__ k_ws,
                                               const ushort* __restrict__ vt_ws,
                                               ushort* __restrict__ ctx) {
    __shared__ float obuf[4][32][65];  // epilogue only; bank = (q+d)%32, conflict-free

    const int t = threadIdx.x, lane = t & 63, w = t >> 6;
    const int l32 = lane & 31, hi = lane >> 5;
    const int bh = blockIdx.y;
    const int q0 = blockIdx.x * 128 + w * 32;

    const ushort* Qg = q_ws + (size_t)bh * S_ * 64;
    const ushort* Kg = k_ws + (size_t)bh * S_ * 64;
    const ushort* Vg = vt_ws + (size_t)bh * 64 * S_;

    // Q fragments: B-operand of QK^T. col=lane&31 -> q=q0+l32; k=8*hi+e -> d.
    s16x8 qf[4];
#pragma unroll
    for (int dc = 0; dc < 4; dc++)
        qf[dc] = *(const s16x8*)&Qg[(size_t)(q0 + l32) * 64 + dc * 16 + hi * 8];

    const f32x16 Z16 = {0.f,0.f,0.f,0.f,0.f,0.f,0.f,0.f,0.f,0.f,0.f,0.f,0.f,0.f,0.f,0.f};
    f32x16 o0 = Z16, o1 = Z16;            // O^T: o0 = d 0..31, o1 = d 32..63
    float m_run = -1e30f, l_run = 0.f;

    const ushort* kp = Kg + (size_t)l32 * 64 + hi * 8;    // + s*64 walks k-rows
    const ushort* vp = Vg + (size_t)l32 * 2048 + hi * 8;  // row d=l32 (dt=0)

    for (int kt = 0; kt < S_ / 64; ++kt) {
        const ushort* kpt = kp + (size_t)kt * 64 * 64;
        const ushort* vpt = vp + kt * 64;

        // ---- QK^T: St = K(32k x 16d) x Q(16d x 32q), 4 d-chunks, 2 k-subtiles
        f32x16 s0 = Z16, s1 = Z16;
#pragma unroll
        for (int dc = 0; dc < 4; dc++) {
            s16x8 kf = *(const s16x8*)(kpt + dc * 16);
            s0 = __builtin_amdgcn_mfma_f32_32x32x16_bf16(kf, qf[dc], s0, 0, 0, 0);
        }
#pragma unroll
        for (int dc = 0; dc < 4; dc++) {
            s16x8 kf = *(const s16x8*)(kpt + 32 * 64 + dc * 16);
            s1 = __builtin_amdgcn_mfma_f32_32x32x16_bf16(kf, qf[dc], s1, 0, 0, 0);
        }

        // ---- online softmax (per-lane row stats; partner lane^32 holds the
        //      complementary 32 kidx for the same q)
        float mx = fmaxf(s0[0], s1[0]);
#pragma unroll
        for (int r = 1; r < 16; r++) mx = fmaxf(mx, fmaxf(s0[r], s1[r]));
        mx = fmaxf(mx, __shfl_xor(mx, 32, 64));
        float mnew = fmaxf(m_run, mx);
        float alpha = __expf(m_run - mnew);
        m_run = mnew;

        float rs = 0.f;
#pragma unroll
        for (int r = 0; r < 16; r++) { s0[r] = __expf(s0[r] - mnew); rs += s0[r]; }
#pragma unroll
        for (int r = 0; r < 16; r++) { s1[r] = __expf(s1[r] - mnew); rs += s1[r]; }
        rs += __shfl_xor(rs, 32, 64);
        l_run = l_run * alpha + rs;

#pragma unroll
        for (int r = 0; r < 16; r++) { o0[r] *= alpha; o1[r] *= alpha; }

        // ---- PV: O^T += Vt(32d x 16k) x P^T(16k x 32q), per k-subtile ks
#pragma unroll
        for (int ks = 0; ks < 2; ks++) {
            const f32x16& p = ks ? s1 : s0;
            // own packed pairs (kidx per lo/hi half documented above)
            uint32_t A0 = pk2(p[0], p[1]),   A1 = pk2(p[2], p[3]);
            uint32_t B0 = pk2(p[4], p[5]),   B1 = pk2(p[6], p[7]);
            uint32_t C0 = pk2(p[8], p[9]),   C1 = pk2(p[10], p[11]);
            uint32_t D0 = pk2(p[12], p[13]), D1 = pk2(p[14], p[15]);
            uint32_t A0x = (uint32_t)__shfl_xor((int)A0, 32, 64);
            uint32_t A1x = (uint32_t)__shfl_xor((int)A1, 32, 64);
            uint32_t B0x = (uint32_t)__shfl_xor((int)B0, 32, 64);
            uint32_t B1x = (uint32_t)__shfl_xor((int)B1, 32, 64);
            uint32_t C0x = (uint32_t)__shfl_xor((int)C0, 32, 64);
            uint32_t C1x = (uint32_t)__shfl_xor((int)C1, 32, 64);
            uint32_t D0x = (uint32_t)__shfl_xor((int)D0, 32, 64);
            uint32_t D1x = (uint32_t)__shfl_xor((int)D1, 32, 64);

            union { uint32_t u[4]; s16x8 h; } F0, F1;
            // chunk0: kidx ks*32 + 0..15   (lo lane k=0..7, hi lane k=8..15)
            F0.u[0] = hi ? B0x : A0;  F0.u[1] = hi ? B1x : A1;
            F0.u[2] = hi ? B0  : A0x; F0.u[3] = hi ? B1  : A1x;
            // chunk1: kidx ks*32 + 16..31
            F1.u[0] = hi ? D0x : C0;  F1.u[1] = hi ? D1x : C1;
            F1.u[2] = hi ? D0  : C0x; F1.u[3] = hi ? D1  : C1x;

            const int kc0 = ks * 2;
            s16x8 v00 = *(const s16x8*)(vpt + kc0 * 16);
            s16x8 v01 = *(const s16x8*)(vpt + (size_t)32 * 2048 + kc0 * 16);
            s16x8 v10 = *(const s16x8*)(vpt + kc0 * 16 + 16);
            s16x8 v11 = *(const s16x8*)(vpt + (size_t)32 * 2048 + kc0 * 16 + 16);
            o0 = __builtin_amdgcn_mfma_f32_32x32x16_bf16(v00, F0.h, o0, 0, 0, 0);
            o1 = __builtin_amdgcn_mfma_f32_32x32x16_bf16(v01, F0.h, o1, 0, 0, 0);
            o0 = __builtin_amdgcn_mfma_f32_32x32x16_bf16(v10, F1.h, o0, 0, 0, 0);
            o1 = __builtin_amdgcn_mfma_f32_32x32x16_bf16(v11, F1.h, o1, 0, 0, 0);
        }
    }

    // ---- epilogue: O^T (rows=d, col-lane=q) -> LDS -> row-major 16B stores
    float inv = 1.0f / l_run;
#pragma unroll
    for (int r = 0; r < 16; r++) {
        int d0 = (r & 3) + 8 * (r >> 2) + 4 * hi;
        obuf[w][l32][d0]      = o0[r] * inv;
        obuf[w][l32][32 + d0] = o1[r] * inv;
    }
    __syncthreads();
    int b_ = bh >> 4, h = bh & 15;
    ushort* gp = ctx + ((size_t)(b_ * 2048 + q0 + l32)) * 1024 + h * 64 + hi * 32;
#pragma unroll
    for (int c = 0; c < 4; c++) {
        s16x8 vv;
#pragma unroll
        for (int j = 0; j < 8; j++) vv[j] = (short)f2bf(obuf[w][l32][hi * 32 + c * 8 + j]);
        *(s16x8*)(gp + c * 8) = vv;
    }
}

extern "C" void kernel_launch(void* const* d_in, const int* in_sizes, int n_in,
                              void* d_out, int out_size, void* d_ws, size_t ws_size,
                              hipStream_t stream) {
    const float* X  = (const float*)d_in[0];
    const float* Wq = (const float*)d_in[1];
    const float* bq = (const float*)d_in[2];
    const float* Wk = (const float*)d_in[3];
    const float* bk = (const float*)d_in[4];
    const float* Wv = (const float*)d_in[5];
    const float* bv = (const float*)d_in[6];
    const float* Wo = (const float*)d_in[7];
    const float* bo = (const float*)d_in[8];
    float* out = (float*)d_out;

    // ws (MiB): wtq@0(2) wtk@2(2) wtv@4(2) wto@6(2) qws@8(8) kws@16(8)
    // ctx@24(8) = 32 MiB. d_out (16 MiB fp32) hosts V^T bf16 @0 (8 MiB) and
    // Xbf16 @8MiB (8 MiB): both dead before the final GEMM overwrites d_out.
    char* ws = (char*)d_ws;
    ushort* wtq  = (ushort*)(ws);
    ushort* wtk  = (ushort*)(ws + ((size_t)2 << 20));
    ushort* wtv  = (ushort*)(ws + ((size_t)4 << 20));
    ushort* wto  = (ushort*)(ws + ((size_t)6 << 20));
    ushort* qws  = (ushort*)(ws + ((size_t)8 << 20));
    ushort* kws  = (ushort*)(ws + ((size_t)16 << 20));
    ushort* ctx  = (ushort*)(ws + ((size_t)24 << 20));
    ushort* vtws = (ushort*)d_out;
    ushort* xbf  = (ushort*)d_out + ((size_t)4 << 20);  // +8 MiB

    transpose_k4<<<dim3(32, 32, 4), dim3(32, 8), 0, stream>>>(Wq, Wk, Wv, Wo,
                                                              wtq, wtk, wtv, wto);
    cast_bf16<<<2048, 256, 0, stream>>>(X, xbf);

    gemm_bt<<<dim3(8, 32, 3), 256, 0, stream>>>(xbf, wtq, wtk, wtv, bq, bk, bv,
                                                qws, kws, vtws, 1);

    attn<<<dim3(S_ / 128, 32), 256, 0, stream>>>(qws, kws, vtws, ctx);

    gemm_bt<<<dim3(8, 32, 1), 256, 0, stream>>>(ctx, wto, wto, wto, bo, bo, bo,
                                                out, out, out, 0);
}

// Round 3
// 276.144 us; speedup vs baseline: 1.0721x; 1.0721x over previous
//
#include <hip/hip_runtime.h>
#include <stdint.h>

#define S_ 2048
#define H_ 16

typedef short s16x8 __attribute__((ext_vector_type(8)));
typedef float f32x4 __attribute__((ext_vector_type(4)));
typedef float f32x16 __attribute__((ext_vector_type(16)));

__device__ __forceinline__ ushort f2bf(float f) {
    union { float f; uint32_t u; } v; v.f = f;
    uint32_t r = v.u + 0x7fffu + ((v.u >> 16) & 1u);
    return (ushort)(r >> 16);
}
__device__ __forceinline__ uint32_t pk2(float a, float b) {
    return (uint32_t)f2bf(a) | ((uint32_t)f2bf(b) << 16);
}

// async global->LDS, 16B per lane. LDS dest is wave-uniform base + lane*16.
__device__ __forceinline__ void gld16(ushort* lds, const ushort* g) {
    auto* gp = reinterpret_cast<uint32_t __attribute__((address_space(1)))*>(
        reinterpret_cast<uintptr_t>(g));
    auto* lp = reinterpret_cast<uint32_t __attribute__((address_space(3)))*>(
        reinterpret_cast<uintptr_t>(lds));
    __builtin_amdgcn_global_load_lds(gp, lp, 16, 0, 0);
}

// ---- X fp32 -> bf16 (one-time pass; same RNE rounding as before) ----
__global__ void cast_bf16(const float* __restrict__ src, ushort* __restrict__ dst) {
    size_t i = ((size_t)blockIdx.x * 256 + threadIdx.x) * 8;
    float4 x = *(const float4*)(src + i);
    float4 y = *(const float4*)(src + i + 4);
    s16x8 r;
    r[0] = (short)f2bf(x.x); r[1] = (short)f2bf(x.y);
    r[2] = (short)f2bf(x.z); r[3] = (short)f2bf(x.w);
    r[4] = (short)f2bf(y.x); r[5] = (short)f2bf(y.y);
    r[6] = (short)f2bf(y.z); r[7] = (short)f2bf(y.w);
    *(s16x8*)(dst + i) = r;
}

// ---- weight prep: dst[n*1024+k] = bf16(src[k*1024+n]), 4 weights in one launch ----
__global__ void transpose_k4(const float* __restrict__ s0, const float* __restrict__ s1,
                             const float* __restrict__ s2, const float* __restrict__ s3,
                             ushort* __restrict__ d0, ushort* __restrict__ d1,
                             ushort* __restrict__ d2, ushort* __restrict__ d3) {
    const int z = blockIdx.z;
    const float* src = (z == 0) ? s0 : (z == 1) ? s1 : (z == 2) ? s2 : s3;
    ushort* dst      = (z == 0) ? d0 : (z == 1) ? d1 : (z == 2) ? d2 : d3;
    __shared__ ushort t[32][33];
    int bx = blockIdx.x * 32, by = blockIdx.y * 32;
    int x = threadIdx.x;
    for (int y = threadIdx.y; y < 32; y += 8)
        t[y][x] = f2bf(src[(size_t)(by + y) * 1024 + bx + x]);
    __syncthreads();
    for (int y = threadIdx.y; y < 32; y += 8)
        dst[(size_t)(bx + y) * 1024 + by + x] = t[x][y];
}

// ---------------- GEMM: C[m,n] = A[M,K] @ Bt[N,K]^T + bias(fp32) ------------
__global__ void gemm_bt(const ushort* __restrict__ A,
                        const ushort* __restrict__ Bt0, const ushort* __restrict__ Bt1,
                        const ushort* __restrict__ Bt2,
                        const float* __restrict__ bi0, const float* __restrict__ bi1,
                        const float* __restrict__ bi2,
                        void* __restrict__ o0, void* __restrict__ o1,
                        void* __restrict__ o2,
                        int mode0) {
    const int z = blockIdx.z;
    const ushort* Bt  = (z == 0) ? Bt0 : (z == 1) ? Bt1 : Bt2;
    const float* bia  = (z == 0) ? bi0 : (z == 1) ? bi1 : bi2;
    void* out         = (z == 0) ? o0  : (z == 1) ? o1  : o2;
    const int mode = mode0 + z;

    __shared__ __align__(16) ushort Asm[128 * 32];
    __shared__ __align__(16) ushort Bsm[128 * 32];

    const int t = threadIdx.x;
    const int lane = t & 63, w = t >> 6;
    const int wm = w >> 1, wn = w & 1;
    const int quad = lane >> 4, l16 = lane & 15;
    const int m0 = blockIdx.y * 128, n0 = blockIdx.x * 128;
    const int K = 1024;

    const f32x4 FZ = {0.f, 0.f, 0.f, 0.f};
    f32x4 acc[4][4];
#pragma unroll
    for (int i = 0; i < 4; i++)
#pragma unroll
        for (int j = 0; j < 4; j++) acc[i][j] = FZ;

    const ushort* Ap = A  + (size_t)(m0 + (t >> 2)) * K + (t & 3) * 8;
    const ushort* Bp = Bt + (size_t)(n0 + (t >> 2)) * K + (t & 3) * 8;
    ushort* AsmW = Asm + w * 512;
    ushort* BsmW = Bsm + w * 512;

    for (int kt = 0; kt < K / 32; ++kt) {
        __syncthreads();
        gld16(AsmW,        Ap + kt * 32);
        gld16(AsmW + 2048, Ap + (size_t)64 * K + kt * 32);
        gld16(BsmW,        Bp + kt * 32);
        gld16(BsmW + 2048, Bp + (size_t)64 * K + kt * 32);
        __syncthreads();

        s16x8 a[4], b[4];
#pragma unroll
        for (int i = 0; i < 4; i++) {
            int row = wm * 64 + i * 16 + l16;
            a[i] = *(const s16x8*)((const char*)Asm + row * 64 + quad * 16);
        }
#pragma unroll
        for (int j = 0; j < 4; j++) {
            int row = wn * 64 + j * 16 + l16;
            b[j] = *(const s16x8*)((const char*)Bsm + row * 64 + quad * 16);
        }
#pragma unroll
        for (int i = 0; i < 4; i++)
#pragma unroll
            for (int j = 0; j < 4; j++)
                acc[i][j] = __builtin_amdgcn_mfma_f32_16x16x32_bf16(a[i], b[j], acc[i][j], 0, 0, 0);
    }

#pragma unroll
    for (int j = 0; j < 4; j++) {
        int n = n0 + wn * 64 + j * 16 + l16;
        float bv = bia[n];
#pragma unroll
        for (int i = 0; i < 4; i++) {
#pragma unroll
            for (int r = 0; r < 4; r++) {
                int m = m0 + wm * 64 + i * 16 + quad * 4 + r;
                float v = acc[i][j][r] + bv;
                if (mode == 0) {
                    ((float*)out)[(size_t)m * 1024 + n] = v;
                } else {
                    int b_ = m >> 11, s = m & 2047;
                    int h = n >> 6, d = n & 63;
                    if (mode == 1)
                        ((ushort*)out)[((size_t)(b_ * 16 + h) * 2048 + s) * 64 + d] = f2bf(v * 0.125f);
                    else if (mode == 2)
                        ((ushort*)out)[((size_t)(b_ * 16 + h) * 2048 + s) * 64 + d] = f2bf(v);
                    else
                        ((ushort*)out)[((size_t)(b_ * 16 + h) * 64 + d) * 2048 + s] = f2bf(v);
                }
            }
        }
    }
}

// ---------------- MFMA flash attention, swapped-operand 32x32, split-K ----------
// grid: (S/64, B*H), 256 threads = 4 waves. Wave w: q-tile (w&1), k-half (w>>1).
// Waves {0,1} cover k-tiles [0,16), waves {2,3} cover [16,32) for the same
// 64 q-rows; partials merge in LDS (flash-decode). 4096 waves -> 16 waves/CU.
// QK^T as St = mfma(K, Q): lane holds col q=lane&31, rows kidx=(r&3)+8*(r>>2)+4*hi.
// PV as O^T = mfma(Vt, P^T): softmax state stays lane-local. (R2-verified math.)
__global__ __launch_bounds__(256, 4) void attn(const ushort* __restrict__ q_ws,
                                               const ushort* __restrict__ k_ws,
                                               const ushort* __restrict__ vt_ws,
                                               ushort* __restrict__ ctx) {
    __shared__ float part[2][64][33];  // partner O^T partials; bank=(lane+r)%32
    __shared__ float pml[2][64][2];    // partner m, l
    __shared__ float obuf[2][32][65];  // epilogue transpose (separate, no alias)

    const int t = threadIdx.x, lane = t & 63, w = t >> 6;
    const int l32 = lane & 31, hi = lane >> 5;
    const int qt = w & 1, khalf = w >> 1;
    const int bh = blockIdx.y;
    const int q0 = blockIdx.x * 64 + qt * 32;

    const ushort* Qg = q_ws + (size_t)bh * S_ * 64;
    const ushort* Kg = k_ws + (size_t)bh * S_ * 64;
    const ushort* Vg = vt_ws + (size_t)bh * 64 * S_;

    // Q fragments: B-operand of QK^T. col=lane&31 -> q=q0+l32; k=8*hi+e -> d.
    s16x8 qf[4];
#pragma unroll
    for (int dc = 0; dc < 4; dc++)
        qf[dc] = *(const s16x8*)&Qg[(size_t)(q0 + l32) * 64 + dc * 16 + hi * 8];

    const f32x16 Z16 = {0.f,0.f,0.f,0.f,0.f,0.f,0.f,0.f,0.f,0.f,0.f,0.f,0.f,0.f,0.f,0.f};
    f32x16 o0 = Z16, o1 = Z16;            // O^T: o0 = d 0..31, o1 = d 32..63
    float m_run = -1e30f, l_run = 0.f;

    const ushort* kp = Kg + (size_t)l32 * 64 + hi * 8;
    const ushort* vp = Vg + (size_t)l32 * 2048 + hi * 8;

    for (int kt = khalf * 16; kt < khalf * 16 + 16; ++kt) {
        const ushort* kpt = kp + (size_t)kt * 64 * 64;
        const ushort* vpt = vp + kt * 64;

        // ---- QK^T: St = K(32k x 16d) x Q(16d x 32q), 2 k-subtiles x 4 d-chunks
        f32x16 s0 = Z16, s1 = Z16;
#pragma unroll
        for (int dc = 0; dc < 4; dc++) {
            s16x8 kf = *(const s16x8*)(kpt + dc * 16);
            s0 = __builtin_amdgcn_mfma_f32_32x32x16_bf16(kf, qf[dc], s0, 0, 0, 0);
        }
#pragma unroll
        for (int dc = 0; dc < 4; dc++) {
            s16x8 kf = *(const s16x8*)(kpt + 32 * 64 + dc * 16);
            s1 = __builtin_amdgcn_mfma_f32_32x32x16_bf16(kf, qf[dc], s1, 0, 0, 0);
        }

        // ---- online softmax; 4-chain fmax tree (depth ~7 vs serial 31)
        float m0 = fmaxf(s0[0], s1[0]);
        float m1 = fmaxf(s0[1], s1[1]);
        float m2 = fmaxf(s0[2], s1[2]);
        float m3 = fmaxf(s0[3], s1[3]);
#pragma unroll
        for (int r = 4; r < 16; r += 4) {
            m0 = fmaxf(m0, fmaxf(s0[r],     s1[r]));
            m1 = fmaxf(m1, fmaxf(s0[r + 1], s1[r + 1]));
            m2 = fmaxf(m2, fmaxf(s0[r + 2], s1[r + 2]));
            m3 = fmaxf(m3, fmaxf(s0[r + 3], s1[r + 3]));
        }
        float mx = fmaxf(fmaxf(m0, m1), fmaxf(m2, m3));
        mx = fmaxf(mx, __shfl_xor(mx, 32, 64));
        float mnew = fmaxf(m_run, mx);
        float alpha = __expf(m_run - mnew);
        m_run = mnew;

        float ra = 0.f, rb = 0.f;
#pragma unroll
        for (int r = 0; r < 16; r++) {
            s0[r] = __expf(s0[r] - mnew); ra += s0[r];
            s1[r] = __expf(s1[r] - mnew); rb += s1[r];
        }
        float rs = ra + rb;
        rs += __shfl_xor(rs, 32, 64);
        l_run = l_run * alpha + rs;

#pragma unroll
        for (int r = 0; r < 16; r++) { o0[r] *= alpha; o1[r] *= alpha; }

        // ---- PV: O^T += Vt(32d x 16k) x P^T(16k x 32q), per k-subtile ks
#pragma unroll
        for (int ks = 0; ks < 2; ks++) {
            const f32x16& p = ks ? s1 : s0;
            uint32_t A0 = pk2(p[0], p[1]),   A1 = pk2(p[2], p[3]);
            uint32_t B0 = pk2(p[4], p[5]),   B1 = pk2(p[6], p[7]);
            uint32_t C0 = pk2(p[8], p[9]),   C1 = pk2(p[10], p[11]);
            uint32_t D0 = pk2(p[12], p[13]), D1 = pk2(p[14], p[15]);
            uint32_t A0x = (uint32_t)__shfl_xor((int)A0, 32, 64);
            uint32_t A1x = (uint32_t)__shfl_xor((int)A1, 32, 64);
            uint32_t B0x = (uint32_t)__shfl_xor((int)B0, 32, 64);
            uint32_t B1x = (uint32_t)__shfl_xor((int)B1, 32, 64);
            uint32_t C0x = (uint32_t)__shfl_xor((int)C0, 32, 64);
            uint32_t C1x = (uint32_t)__shfl_xor((int)C1, 32, 64);
            uint32_t D0x = (uint32_t)__shfl_xor((int)D0, 32, 64);
            uint32_t D1x = (uint32_t)__shfl_xor((int)D1, 32, 64);

            union { uint32_t u[4]; s16x8 h; } F0, F1;
            F0.u[0] = hi ? B0x : A0;  F0.u[1] = hi ? B1x : A1;
            F0.u[2] = hi ? B0  : A0x; F0.u[3] = hi ? B1  : A1x;
            F1.u[0] = hi ? D0x : C0;  F1.u[1] = hi ? D1x : C1;
            F1.u[2] = hi ? D0  : C0x; F1.u[3] = hi ? D1  : C1x;

            const int kc0 = ks * 2;
            s16x8 v00 = *(const s16x8*)(vpt + kc0 * 16);
            s16x8 v01 = *(const s16x8*)(vpt + (size_t)32 * 2048 + kc0 * 16);
            s16x8 v10 = *(const s16x8*)(vpt + kc0 * 16 + 16);
            s16x8 v11 = *(const s16x8*)(vpt + (size_t)32 * 2048 + kc0 * 16 + 16);
            o0 = __builtin_amdgcn_mfma_f32_32x32x16_bf16(v00, F0.h, o0, 0, 0, 0);
            o1 = __builtin_amdgcn_mfma_f32_32x32x16_bf16(v01, F0.h, o1, 0, 0, 0);
            o0 = __builtin_amdgcn_mfma_f32_32x32x16_bf16(v10, F1.h, o0, 0, 0, 0);
            o1 = __builtin_amdgcn_mfma_f32_32x32x16_bf16(v11, F1.h, o1, 0, 0, 0);
        }
    }

    // ---- split-K merge: khalf=1 waves publish partials, khalf=0 waves combine
    if (khalf == 1) {
#pragma unroll
        for (int r = 0; r < 16; r++) {
            part[qt][lane][r]      = o0[r];
            part[qt][lane][16 + r] = o1[r];
        }
        pml[qt][lane][0] = m_run;
        pml[qt][lane][1] = l_run;
    }
    __syncthreads();
    if (khalf == 1) return;

    {
        float m2 = pml[qt][lane][0], l2 = pml[qt][lane][1];
        float mm = fmaxf(m_run, m2);
        float a1 = __expf(m_run - mm), a2 = __expf(m2 - mm);
#pragma unroll
        for (int r = 0; r < 16; r++) {
            o0[r] = o0[r] * a1 + part[qt][lane][r] * a2;
            o1[r] = o1[r] * a1 + part[qt][lane][16 + r] * a2;
        }
        l_run = l_run * a1 + l2 * a2;
    }

    // ---- epilogue: O^T -> per-wave LDS transpose -> row-major 16B stores
    float inv = 1.0f / l_run;
#pragma unroll
    for (int r = 0; r < 16; r++) {
        int d0 = (r & 3) + 8 * (r >> 2) + 4 * hi;
        obuf[qt][l32][d0]      = o0[r] * inv;
        obuf[qt][l32][32 + d0] = o1[r] * inv;
    }
    // obuf[qt] is private to this wave: wave-level LDS drain suffices
    asm volatile("s_waitcnt lgkmcnt(0)" ::: "memory");
    __builtin_amdgcn_sched_barrier(0);
    int b_ = bh >> 4, h = bh & 15;
    ushort* gp = ctx + ((size_t)(b_ * 2048 + q0 + l32)) * 1024 + h * 64 + hi * 32;
#pragma unroll
    for (int c = 0; c < 4; c++) {
        s16x8 vv;
#pragma unroll
        for (int j = 0; j < 8; j++) vv[j] = (short)f2bf(obuf[qt][l32][hi * 32 + c * 8 + j]);
        *(s16x8*)(gp + c * 8) = vv;
    }
}

extern "C" void kernel_launch(void* const* d_in, const int* in_sizes, int n_in,
                              void* d_out, int out_size, void* d_ws, size_t ws_size,
                              hipStream_t stream) {
    const float* X  = (const float*)d_in[0];
    const float* Wq = (const float*)d_in[1];
    const float* bq = (const float*)d_in[2];
    const float* Wk = (const float*)d_in[3];
    const float* bk = (const float*)d_in[4];
    const float* Wv = (const float*)d_in[5];
    const float* bv = (const float*)d_in[6];
    const float* Wo = (const float*)d_in[7];
    const float* bo = (const float*)d_in[8];
    float* out = (float*)d_out;

    // ws (MiB): wtq@0(2) wtk@2(2) wtv@4(2) wto@6(2) qws@8(8) kws@16(8)
    // ctx@24(8) = 32 MiB. d_out (16 MiB fp32) hosts V^T bf16 @0 (8 MiB) and
    // Xbf16 @8MiB (8 MiB): both dead before the final GEMM overwrites d_out.
    char* ws = (char*)d_ws;
    ushort* wtq  = (ushort*)(ws);
    ushort* wtk  = (ushort*)(ws + ((size_t)2 << 20));
    ushort* wtv  = (ushort*)(ws + ((size_t)4 << 20));
    ushort* wto  = (ushort*)(ws + ((size_t)6 << 20));
    ushort* qws  = (ushort*)(ws + ((size_t)8 << 20));
    ushort* kws  = (ushort*)(ws + ((size_t)16 << 20));
    ushort* ctx  = (ushort*)(ws + ((size_t)24 << 20));
    ushort* vtws = (ushort*)d_out;
    ushort* xbf  = (ushort*)d_out + ((size_t)4 << 20);  // +8 MiB

    transpose_k4<<<dim3(32, 32, 4), dim3(32, 8), 0, stream>>>(Wq, Wk, Wv, Wo,
                                                              wtq, wtk, wtv, wto);
    cast_bf16<<<2048, 256, 0, stream>>>(X, xbf);

    gemm_bt<<<dim3(8, 32, 3), 256, 0, stream>>>(xbf, wtq, wtk, wtv, bq, bk, bv,
                                                qws, kws, vtws, 1);

    attn<<<dim3(S_ / 64, 32), 256, 0, stream>>>(qws, kws, vtws, ctx);

    gemm_bt<<<dim3(8, 32, 1), 256, 0, stream>>>(ctx, wto, wto, wto, bo, bo, bo,
                                                out, out, out, 0);
}